// Round 8
// baseline (261.834 us; speedup 1.0000x reference)
//
#include <hip/hip_runtime.h>
#include <hip/hip_bf16.h>
#include <hip/hip_fp16.h>
#include <math.h>

#define N_NODES 50000
#define N_EDGES 800000
#define CH 128
#define SCAN_BLOCKS ((N_NODES + 255) / 256)   // 196

// ---------------------------------------------------------------------------
// Kernel 1: xt (fp16) = x @ W^T + b
// 256 threads = 32 col-groups (4 cols) x 8 row-groups (4 rows) -> 32r x 128c
// tile. W^T in LDS with the XOR swizzle proven 0-conflict in round 3.
// xs is row-major [32][128]: float4 coalesced writes + scalar broadcast
// reads (also proven 0-conflict in round 3). Per k: 4 b32 + 1 b128 LDS
// reads feed 16 fp32 FMAs (4 rows x 4 cols register block).
// ---------------------------------------------------------------------------
__global__ __launch_bounds__(256) void gemm_xt_f16(const float* __restrict__ x,
                                                   const float* __restrict__ W,
                                                   const float* __restrict__ bias_p,
                                                   __half* __restrict__ xt,
                                                   int rows_per_block) {
    __shared__ float wt[128 * 128];   // 64 KB
    __shared__ float xs[32][128];     // 16 KB, row-major

    const int tid = threadIdx.x;
    const int cg  = tid & 31;   // col group (4 cols)
    const int rg  = tid >> 5;   // row group (4 rows), 0..7

    for (int i = tid; i < 128 * 128; i += 256) {
        int c = i >> 7, k = i & 127;
        wt[(k << 7) + ((((c >> 2) ^ (k & 31))) << 2) + (c & 3)] = W[i];
    }
    const float4 bias = reinterpret_cast<const float4*>(bias_p)[cg];
    __syncthreads();

    const int row0    = blockIdx.x * rows_per_block;
    const int row_end = min(row0 + rows_per_block, N_NODES);

    for (int rb = row0; rb < row_end; rb += 32) {
        // stage 32 rows of x, row-major, float4 coalesced (round-3 pattern)
        #pragma unroll
        for (int p = 0; p < 4; ++p) {
            const int r    = p * 8 + rg;
            const int grow = rb + r;
            float4 f = {0.f, 0.f, 0.f, 0.f};
            if (grow < N_NODES)
                f = reinterpret_cast<const float4*>(&x[(size_t)grow * CH])[cg];
            reinterpret_cast<float4*>(&xs[r][0])[cg] = f;
        }
        __syncthreads();

        float acc[4][4];
        #pragma unroll
        for (int i = 0; i < 4; ++i)
            #pragma unroll
            for (int j = 0; j < 4; ++j) acc[i][j] = 0.f;

        const int r0 = 4 * rg;
        #pragma unroll 8
        for (int k = 0; k < 128; ++k) {
            const float4 wv = *reinterpret_cast<const float4*>(
                &wt[(k << 7) + ((cg ^ (k & 31)) << 2)]);
            const float x0 = xs[r0 + 0][k];   // broadcast b32 reads
            const float x1 = xs[r0 + 1][k];
            const float x2 = xs[r0 + 2][k];
            const float x3 = xs[r0 + 3][k];
            acc[0][0] += x0 * wv.x; acc[0][1] += x0 * wv.y;
            acc[0][2] += x0 * wv.z; acc[0][3] += x0 * wv.w;
            acc[1][0] += x1 * wv.x; acc[1][1] += x1 * wv.y;
            acc[1][2] += x1 * wv.z; acc[1][3] += x1 * wv.w;
            acc[2][0] += x2 * wv.x; acc[2][1] += x2 * wv.y;
            acc[2][2] += x2 * wv.z; acc[2][3] += x2 * wv.w;
            acc[3][0] += x3 * wv.x; acc[3][1] += x3 * wv.y;
            acc[3][2] += x3 * wv.z; acc[3][3] += x3 * wv.w;
        }

        #pragma unroll
        for (int i = 0; i < 4; ++i) {
            const int grow = rb + r0 + i;
            if (grow < N_NODES) {
                float2 lo = make_float2(acc[i][0] + bias.x, acc[i][1] + bias.y);
                float2 hi = make_float2(acc[i][2] + bias.z, acc[i][3] + bias.w);
                __half2 h01 = __float22half2_rn(lo);
                __half2 h23 = __float22half2_rn(hi);
                uint2 pk;
                pk.x = *reinterpret_cast<unsigned int*>(&h01);
                pk.y = *reinterpret_cast<unsigned int*>(&h23);
                *reinterpret_cast<uint2*>(&xt[(size_t)grow * CH + 4 * cg]) = pk;
            }
        }
        __syncthreads();
    }
}

// ---------------------------------------------------------------------------
// CSR build — parallel scan version
// ---------------------------------------------------------------------------
__global__ __launch_bounds__(256) void hist_deg(const int* __restrict__ ei,
                                                int* __restrict__ deg) {
    const int e = blockIdx.x * 256 + threadIdx.x;
    if (e < N_EDGES) atomicAdd(&deg[ei[e]], 1);
}

// Block-local exclusive prefix of deg -> offs; block totals -> psum.
__global__ __launch_bounds__(256) void scan_local(const int* __restrict__ deg,
                                                  int* __restrict__ offs,
                                                  int* __restrict__ psum) {
    __shared__ int s[256];
    const int t = threadIdx.x;
    const int i = blockIdx.x * 256 + t;
    const int d = (i < N_NODES) ? deg[i] : 0;
    s[t] = d;
    __syncthreads();
    #pragma unroll
    for (int off = 1; off < 256; off <<= 1) {   // Hillis-Steele inclusive
        int v = (t >= off) ? s[t - off] : 0;
        __syncthreads();
        s[t] += v;
        __syncthreads();
    }
    if (i < N_NODES) offs[i] = s[t] - d;        // exclusive, block-local
    if (t == 255) psum[blockIdx.x] = s[255];
}

// Exclusive scan of the SCAN_BLOCKS block totals -> pbase.
__global__ __launch_bounds__(256) void scan_psum(const int* __restrict__ psum,
                                                 int* __restrict__ pbase) {
    __shared__ int s[256];
    const int t = threadIdx.x;
    const int v = (t < SCAN_BLOCKS) ? psum[t] : 0;
    s[t] = v;
    __syncthreads();
    #pragma unroll
    for (int off = 1; off < 256; off <<= 1) {
        int u = (t >= off) ? s[t - off] : 0;
        __syncthreads();
        s[t] += u;
        __syncthreads();
    }
    if (t < SCAN_BLOCKS) pbase[t] = s[t] - v;
}

// After this kernel offs[r] = LOCAL segment end; global end = offs[r]+pbase[r>>8].
__global__ __launch_bounds__(256) void fill_csr(const int* __restrict__ ei,
                                                int* __restrict__ offs,
                                                const int* __restrict__ pbase,
                                                int* __restrict__ csr) {
    const int e = blockIdx.x * 256 + threadIdx.x;
    if (e < N_EDGES) {
        const int r = ei[e];
        const int p = atomicAdd(&offs[r], 1) + pbase[r >> 8];
        csr[p] = ei[N_EDGES + e];
    }
}

// ---------------------------------------------------------------------------
// Gather: one wave per node, 64 lanes x 2 fp16 channels. tanh fused.
// Global segment of node n: [ offs[n-1]+pbase[(n-1)>>8]  (0 if n==0),
//                             offs[n]+pbase[n>>8] )     after fill_csr.
// ---------------------------------------------------------------------------
__global__ __launch_bounds__(256) void gather_tanh(const int* __restrict__ offs,
                                                   const int* __restrict__ pbase,
                                                   const int* __restrict__ csr,
                                                   const __half* __restrict__ xt,
                                                   float* __restrict__ out) {
    const int wave = (blockIdx.x * 256 + threadIdx.x) >> 6;
    if (wave >= N_NODES) return;
    const int lane = threadIdx.x & 63;
    const int start = (wave == 0) ? 0 : offs[wave - 1] + pbase[(wave - 1) >> 8];
    const int end   = offs[wave] + pbase[wave >> 8];

    float ax = 0.f, ay = 0.f;
    int i = start;
    for (; i + 4 <= end; i += 4) {
        const int c0 = csr[i], c1 = csr[i + 1], c2 = csr[i + 2], c3 = csr[i + 3];
        const float2 v0 = __half22float2(*reinterpret_cast<const __half2*>(
            &xt[(size_t)c0 * CH + lane * 2]));
        const float2 v1 = __half22float2(*reinterpret_cast<const __half2*>(
            &xt[(size_t)c1 * CH + lane * 2]));
        const float2 v2 = __half22float2(*reinterpret_cast<const __half2*>(
            &xt[(size_t)c2 * CH + lane * 2]));
        const float2 v3 = __half22float2(*reinterpret_cast<const __half2*>(
            &xt[(size_t)c3 * CH + lane * 2]));
        ax += v0.x + v1.x + v2.x + v3.x;
        ay += v0.y + v1.y + v2.y + v3.y;
    }
    for (; i < end; ++i) {
        const int c = csr[i];
        const float2 v = __half22float2(*reinterpret_cast<const __half2*>(
            &xt[(size_t)c * CH + lane * 2]));
        ax += v.x; ay += v.y;
    }
    float2 o;
    o.x = tanhf(ax);
    o.y = tanhf(ay);
    *reinterpret_cast<float2*>(&out[(size_t)wave * CH + lane * 2]) = o;
}

// ---------------------------------------------------------------------------
// Fallback path (ws too small): atomic scatter + tanh
// ---------------------------------------------------------------------------
__global__ __launch_bounds__(256) void scatter_add(const int* __restrict__ ei,
                                                   const __half* __restrict__ xt,
                                                   float* __restrict__ out) {
    const int gid = blockIdx.x * 256 + threadIdx.x;
    const int e = gid >> 5;
    if (e >= N_EDGES) return;
    const int lane = gid & 31;
    const int row = ei[e];
    const int col = ei[N_EDGES + e];
    const float2 va = __half22float2(*reinterpret_cast<const __half2*>(
        &xt[(size_t)col * CH + lane * 4]));
    const float2 vb = __half22float2(*reinterpret_cast<const __half2*>(
        &xt[(size_t)col * CH + lane * 4 + 2]));
    float* dst = &out[(size_t)row * CH + lane * 4];
    atomicAdd(dst + 0, va.x);
    atomicAdd(dst + 1, va.y);
    atomicAdd(dst + 2, vb.x);
    atomicAdd(dst + 3, vb.y);
}

__global__ __launch_bounds__(256) void tanh_inplace(float* __restrict__ out) {
    const int i = blockIdx.x * 256 + threadIdx.x;
    if (i < N_NODES * CH / 4) {
        float4* p = reinterpret_cast<float4*>(out);
        float4 v = p[i];
        v.x = tanhf(v.x); v.y = tanhf(v.y);
        v.z = tanhf(v.z); v.w = tanhf(v.w);
        p[i] = v;
    }
}

extern "C" void kernel_launch(void* const* d_in, const int* in_sizes, int n_in,
                              void* d_out, int out_size, void* d_ws, size_t ws_size,
                              hipStream_t stream) {
    const float* x  = (const float*)d_in[0];
    const int*   ei = (const int*)d_in[1];
    const float* W  = (const float*)d_in[2];
    const float* b  = (const float*)d_in[3];
    float* out = (float*)d_out;

    // ws layout (xt fp16)
    const size_t XT_B    = (size_t)N_NODES * CH * sizeof(__half); // 12,800,000
    const size_t DEG_O   = XT_B;
    const size_t OFFS_O  = DEG_O  + (size_t)N_NODES * 4;
    const size_t PSUM_O  = OFFS_O + (size_t)(N_NODES + 1) * 4;
    const size_t PBASE_O = PSUM_O + (size_t)SCAN_BLOCKS * 4;
    size_t CSR_O = PBASE_O + (size_t)SCAN_BLOCKS * 4;
    CSR_O = (CSR_O + 255) & ~(size_t)255;
    const size_t NEED = CSR_O + (size_t)N_EDGES * 4;

    __half* xt = (__half*)d_ws;

    const int rpb = 96;                                // rows per block (mult of 32)
    const int gblocks = (N_NODES + rpb - 1) / rpb;     // 521
    gemm_xt_f16<<<gblocks, 256, 0, stream>>>(x, W, b, xt, rpb);

    if (ws_size >= NEED) {
        int* deg   = (int*)((char*)d_ws + DEG_O);
        int* offs  = (int*)((char*)d_ws + OFFS_O);
        int* psum  = (int*)((char*)d_ws + PSUM_O);
        int* pbase = (int*)((char*)d_ws + PBASE_O);
        int* csr   = (int*)((char*)d_ws + CSR_O);

        hipMemsetAsync(deg, 0, (size_t)N_NODES * 4, stream);
        const int eblocks = (N_EDGES + 255) / 256;
        hist_deg<<<eblocks, 256, 0, stream>>>(ei, deg);
        scan_local<<<SCAN_BLOCKS, 256, 0, stream>>>(deg, offs, psum);
        scan_psum<<<1, 256, 0, stream>>>(psum, pbase);
        fill_csr<<<eblocks, 256, 0, stream>>>(ei, offs, pbase, csr);

        const int nblocks = (N_NODES * 64 + 255) / 256;  // one wave per node
        gather_tanh<<<nblocks, 256, 0, stream>>>(offs, pbase, csr, xt, out);
    } else {
        hipMemsetAsync(d_out, 0, (size_t)N_NODES * CH * sizeof(float), stream);
        const int sblocks = (N_EDGES * 32 + 255) / 256;
        scatter_add<<<sblocks, 256, 0, stream>>>(ei, xt, out);
        const int tblocks = (N_NODES * CH / 4 + 255) / 256;
        tanh_inplace<<<tblocks, 256, 0, stream>>>(out);
    }
}

// Round 9
// 235.813 us; speedup vs baseline: 1.1103x; 1.1103x over previous
//
#include <hip/hip_runtime.h>
#include <hip/hip_bf16.h>
#include <hip/hip_fp16.h>
#include <math.h>

#define N_NODES 50000
#define N_EDGES 800000
#define CH 128

// ---------------------------------------------------------------------------
// Kernel 1: xt (fp16) = x @ W^T + b   (unchanged from round 8)
// 256 threads = 32 col-groups (4 cols) x 8 row-groups (4 rows) -> 32r x 128c
// tile. W^T in LDS with the XOR swizzle proven 0-conflict in round 3.
// xs row-major [32][128]: float4 coalesced writes + broadcast reads.
// Per k: 4 b32 + 1 b128 LDS reads feed 16 fp32 FMAs.
// ---------------------------------------------------------------------------
__global__ __launch_bounds__(256) void gemm_xt_f16(const float* __restrict__ x,
                                                   const float* __restrict__ W,
                                                   const float* __restrict__ bias_p,
                                                   __half* __restrict__ xt,
                                                   int rows_per_block) {
    __shared__ float wt[128 * 128];   // 64 KB
    __shared__ float xs[32][128];     // 16 KB, row-major

    const int tid = threadIdx.x;
    const int cg  = tid & 31;   // col group (4 cols)
    const int rg  = tid >> 5;   // row group (4 rows), 0..7

    for (int i = tid; i < 128 * 128; i += 256) {
        int c = i >> 7, k = i & 127;
        wt[(k << 7) + ((((c >> 2) ^ (k & 31))) << 2) + (c & 3)] = W[i];
    }
    const float4 bias = reinterpret_cast<const float4*>(bias_p)[cg];
    __syncthreads();

    const int row0    = blockIdx.x * rows_per_block;
    const int row_end = min(row0 + rows_per_block, N_NODES);

    for (int rb = row0; rb < row_end; rb += 32) {
        #pragma unroll
        for (int p = 0; p < 4; ++p) {
            const int r    = p * 8 + rg;
            const int grow = rb + r;
            float4 f = {0.f, 0.f, 0.f, 0.f};
            if (grow < N_NODES)
                f = reinterpret_cast<const float4*>(&x[(size_t)grow * CH])[cg];
            reinterpret_cast<float4*>(&xs[r][0])[cg] = f;
        }
        __syncthreads();

        float acc[4][4];
        #pragma unroll
        for (int i = 0; i < 4; ++i)
            #pragma unroll
            for (int j = 0; j < 4; ++j) acc[i][j] = 0.f;

        const int r0 = 4 * rg;
        #pragma unroll 8
        for (int k = 0; k < 128; ++k) {
            const float4 wv = *reinterpret_cast<const float4*>(
                &wt[(k << 7) + ((cg ^ (k & 31)) << 2)]);
            const float x0 = xs[r0 + 0][k];   // broadcast b32 reads
            const float x1 = xs[r0 + 1][k];
            const float x2 = xs[r0 + 2][k];
            const float x3 = xs[r0 + 3][k];
            acc[0][0] += x0 * wv.x; acc[0][1] += x0 * wv.y;
            acc[0][2] += x0 * wv.z; acc[0][3] += x0 * wv.w;
            acc[1][0] += x1 * wv.x; acc[1][1] += x1 * wv.y;
            acc[1][2] += x1 * wv.z; acc[1][3] += x1 * wv.w;
            acc[2][0] += x2 * wv.x; acc[2][1] += x2 * wv.y;
            acc[2][2] += x2 * wv.z; acc[2][3] += x2 * wv.w;
            acc[3][0] += x3 * wv.x; acc[3][1] += x3 * wv.y;
            acc[3][2] += x3 * wv.z; acc[3][3] += x3 * wv.w;
        }

        #pragma unroll
        for (int i = 0; i < 4; ++i) {
            const int grow = rb + r0 + i;
            if (grow < N_NODES) {
                float2 lo = make_float2(acc[i][0] + bias.x, acc[i][1] + bias.y);
                float2 hi = make_float2(acc[i][2] + bias.z, acc[i][3] + bias.w);
                __half2 h01 = __float22half2_rn(lo);
                __half2 h23 = __float22half2_rn(hi);
                uint2 pk;
                pk.x = *reinterpret_cast<unsigned int*>(&h01);
                pk.y = *reinterpret_cast<unsigned int*>(&h23);
                *reinterpret_cast<uint2*>(&xt[(size_t)grow * CH + 4 * cg]) = pk;
            }
        }
        __syncthreads();
    }
}

// ---------------------------------------------------------------------------
// Linked-list adjacency build. Two chains per node (parity of e) to halve
// chase depth. ll[e] = {next_edge, col} packed in 8B so each hop fetches
// ONE cache line. ll writes are coalesced (indexed by e) — this replaces
// fill_csr's 53 MB of scattered line writebacks with ~7 MB coalesced.
// head must be preset to 0xFF (-1) via hipMemsetAsync.
// ---------------------------------------------------------------------------
__global__ __launch_bounds__(256) void build_ll(const int* __restrict__ ei,
                                                int* __restrict__ head,
                                                int2* __restrict__ ll) {
    const int e = blockIdx.x * 256 + threadIdx.x;
    if (e < N_EDGES) {
        const int row = ei[e];
        const int col = ei[N_EDGES + e];
        const int h   = ((e & 1) ? N_NODES : 0) + row;
        const int old = atomicExch(&head[h], e);
        ll[e] = make_int2(old, col);
    }
}

// ---------------------------------------------------------------------------
// Gather: one wave per node, 64 lanes x 2 fp16 channels, tanh fused.
// Chases the node's two chains interleaved (wave-uniform control flow;
// 2-way ILP on the serial pointer spine). Chain loads are same-address
// across the wave -> single merged request + broadcast.
// ---------------------------------------------------------------------------
__global__ __launch_bounds__(256) void gather_tanh(const int* __restrict__ head,
                                                   const int2* __restrict__ ll,
                                                   const __half* __restrict__ xt,
                                                   float* __restrict__ out) {
    const int node = (blockIdx.x * 256 + threadIdx.x) >> 6;
    if (node >= N_NODES) return;
    const int lane = threadIdx.x & 63;

    int e0 = head[node];
    int e1 = head[N_NODES + node];

    float ax = 0.f, ay = 0.f;
    while (e0 >= 0 || e1 >= 0) {
        int n0 = -1, c0 = -1, n1 = -1, c1 = -1;
        if (e0 >= 0) { const int2 t = ll[e0]; n0 = t.x; c0 = t.y; }
        if (e1 >= 0) { const int2 t = ll[e1]; n1 = t.x; c1 = t.y; }
        if (c0 >= 0) {
            const float2 v = __half22float2(*reinterpret_cast<const __half2*>(
                &xt[(size_t)c0 * CH + lane * 2]));
            ax += v.x; ay += v.y;
        }
        if (c1 >= 0) {
            const float2 v = __half22float2(*reinterpret_cast<const __half2*>(
                &xt[(size_t)c1 * CH + lane * 2]));
            ax += v.x; ay += v.y;
        }
        e0 = n0; e1 = n1;
    }

    float2 o;
    o.x = tanhf(ax);
    o.y = tanhf(ay);
    *reinterpret_cast<float2*>(&out[(size_t)node * CH + lane * 2]) = o;
}

// ---------------------------------------------------------------------------
// Fallback path (ws too small): atomic scatter + tanh
// ---------------------------------------------------------------------------
__global__ __launch_bounds__(256) void scatter_add(const int* __restrict__ ei,
                                                   const __half* __restrict__ xt,
                                                   float* __restrict__ out) {
    const int gid = blockIdx.x * 256 + threadIdx.x;
    const int e = gid >> 5;
    if (e >= N_EDGES) return;
    const int lane = gid & 31;
    const int row = ei[e];
    const int col = ei[N_EDGES + e];
    const float2 va = __half22float2(*reinterpret_cast<const __half2*>(
        &xt[(size_t)col * CH + lane * 4]));
    const float2 vb = __half22float2(*reinterpret_cast<const __half2*>(
        &xt[(size_t)col * CH + lane * 4 + 2]));
    float* dst = &out[(size_t)row * CH + lane * 4];
    atomicAdd(dst + 0, va.x);
    atomicAdd(dst + 1, va.y);
    atomicAdd(dst + 2, vb.x);
    atomicAdd(dst + 3, vb.y);
}

__global__ __launch_bounds__(256) void tanh_inplace(float* __restrict__ out) {
    const int i = blockIdx.x * 256 + threadIdx.x;
    if (i < N_NODES * CH / 4) {
        float4* p = reinterpret_cast<float4*>(out);
        float4 v = p[i];
        v.x = tanhf(v.x); v.y = tanhf(v.y);
        v.z = tanhf(v.z); v.w = tanhf(v.w);
        p[i] = v;
    }
}

extern "C" void kernel_launch(void* const* d_in, const int* in_sizes, int n_in,
                              void* d_out, int out_size, void* d_ws, size_t ws_size,
                              hipStream_t stream) {
    const float* x  = (const float*)d_in[0];
    const int*   ei = (const int*)d_in[1];
    const float* W  = (const float*)d_in[2];
    const float* b  = (const float*)d_in[3];
    float* out = (float*)d_out;

    // ws layout: xt fp16 | head (2*N ints) | ll (E int2, 8B-aligned)
    const size_t XT_B    = (size_t)N_NODES * CH * sizeof(__half); // 12,800,000
    const size_t HEAD_O  = XT_B;
    size_t LL_O = HEAD_O + (size_t)(2 * N_NODES) * 4;
    LL_O = (LL_O + 255) & ~(size_t)255;
    const size_t NEED = LL_O + (size_t)N_EDGES * 8;               // ~19.6 MB

    __half* xt = (__half*)d_ws;

    const int rpb = 96;                                // rows per block (mult of 32)
    const int gblocks = (N_NODES + rpb - 1) / rpb;     // 521
    gemm_xt_f16<<<gblocks, 256, 0, stream>>>(x, W, b, xt, rpb);

    if (ws_size >= NEED) {
        int*  head = (int*)((char*)d_ws + HEAD_O);
        int2* ll   = (int2*)((char*)d_ws + LL_O);

        hipMemsetAsync(head, 0xFF, (size_t)(2 * N_NODES) * 4, stream);  // -1
        const int eblocks = (N_EDGES + 255) / 256;
        build_ll<<<eblocks, 256, 0, stream>>>(ei, head, ll);

        const int nblocks = (N_NODES * 64 + 255) / 256;  // one wave per node
        gather_tanh<<<nblocks, 256, 0, stream>>>(head, ll, xt, out);
    } else {
        hipMemsetAsync(d_out, 0, (size_t)N_NODES * CH * sizeof(float), stream);
        const int sblocks = (N_EDGES * 32 + 255) / 256;
        scatter_add<<<sblocks, 256, 0, stream>>>(ei, xt, out);
        const int tblocks = (N_NODES * CH / 4 + 255) / 256;
        tanh_inplace<<<tblocks, 256, 0, stream>>>(out);
    }
}

// Round 10
// 230.260 us; speedup vs baseline: 1.1371x; 1.0241x over previous
//
#include <hip/hip_runtime.h>
#include <hip/hip_bf16.h>
#include <hip/hip_fp16.h>
#include <math.h>

#define N_NODES 50000
#define N_EDGES 800000
#define CH 128

// ---------------------------------------------------------------------------
// Kernel 1: xt (fp16) = x @ W^T + b   (unchanged from round 8/9)
// ---------------------------------------------------------------------------
__global__ __launch_bounds__(256) void gemm_xt_f16(const float* __restrict__ x,
                                                   const float* __restrict__ W,
                                                   const float* __restrict__ bias_p,
                                                   __half* __restrict__ xt,
                                                   int rows_per_block) {
    __shared__ float wt[128 * 128];   // 64 KB
    __shared__ float xs[32][128];     // 16 KB, row-major

    const int tid = threadIdx.x;
    const int cg  = tid & 31;   // col group (4 cols)
    const int rg  = tid >> 5;   // row group (4 rows), 0..7

    for (int i = tid; i < 128 * 128; i += 256) {
        int c = i >> 7, k = i & 127;
        wt[(k << 7) + ((((c >> 2) ^ (k & 31))) << 2) + (c & 3)] = W[i];
    }
    const float4 bias = reinterpret_cast<const float4*>(bias_p)[cg];
    __syncthreads();

    const int row0    = blockIdx.x * rows_per_block;
    const int row_end = min(row0 + rows_per_block, N_NODES);

    for (int rb = row0; rb < row_end; rb += 32) {
        #pragma unroll
        for (int p = 0; p < 4; ++p) {
            const int r    = p * 8 + rg;
            const int grow = rb + r;
            float4 f = {0.f, 0.f, 0.f, 0.f};
            if (grow < N_NODES)
                f = reinterpret_cast<const float4*>(&x[(size_t)grow * CH])[cg];
            reinterpret_cast<float4*>(&xs[r][0])[cg] = f;
        }
        __syncthreads();

        float acc[4][4];
        #pragma unroll
        for (int i = 0; i < 4; ++i)
            #pragma unroll
            for (int j = 0; j < 4; ++j) acc[i][j] = 0.f;

        const int r0 = 4 * rg;
        #pragma unroll 8
        for (int k = 0; k < 128; ++k) {
            const float4 wv = *reinterpret_cast<const float4*>(
                &wt[(k << 7) + ((cg ^ (k & 31)) << 2)]);
            const float x0 = xs[r0 + 0][k];   // broadcast b32 reads
            const float x1 = xs[r0 + 1][k];
            const float x2 = xs[r0 + 2][k];
            const float x3 = xs[r0 + 3][k];
            acc[0][0] += x0 * wv.x; acc[0][1] += x0 * wv.y;
            acc[0][2] += x0 * wv.z; acc[0][3] += x0 * wv.w;
            acc[1][0] += x1 * wv.x; acc[1][1] += x1 * wv.y;
            acc[1][2] += x1 * wv.z; acc[1][3] += x1 * wv.w;
            acc[2][0] += x2 * wv.x; acc[2][1] += x2 * wv.y;
            acc[2][2] += x2 * wv.z; acc[2][3] += x2 * wv.w;
            acc[3][0] += x3 * wv.x; acc[3][1] += x3 * wv.y;
            acc[3][2] += x3 * wv.z; acc[3][3] += x3 * wv.w;
        }

        #pragma unroll
        for (int i = 0; i < 4; ++i) {
            const int grow = rb + r0 + i;
            if (grow < N_NODES) {
                float2 lo = make_float2(acc[i][0] + bias.x, acc[i][1] + bias.y);
                float2 hi = make_float2(acc[i][2] + bias.z, acc[i][3] + bias.w);
                __half2 h01 = __float22half2_rn(lo);
                __half2 h23 = __float22half2_rn(hi);
                uint2 pk;
                pk.x = *reinterpret_cast<unsigned int*>(&h01);
                pk.y = *reinterpret_cast<unsigned int*>(&h23);
                *reinterpret_cast<uint2*>(&xt[(size_t)grow * CH + 4 * cg]) = pk;
            }
        }
        __syncthreads();
    }
}

// ---------------------------------------------------------------------------
// Linked-list adjacency build — FOUR chains per node (e&3) to cut the
// serial chase depth to ~deg/4 and give each gather wave 4 independent
// outstanding chain loads. ll[e] = {next, col} in 8B (one line per hop).
// ll writes coalesced by e. head preset to -1 via hipMemsetAsync.
// ---------------------------------------------------------------------------
__global__ __launch_bounds__(256) void build_ll(const int* __restrict__ ei,
                                                int* __restrict__ head,
                                                int2* __restrict__ ll) {
    const int e = blockIdx.x * 256 + threadIdx.x;
    if (e < N_EDGES) {
        const int row = ei[e];
        const int col = ei[N_EDGES + e];
        const int h   = (e & 3) * N_NODES + row;
        const int old = atomicExch(&head[h], e);
        ll[e] = make_int2(old, col);
    }
}

// ---------------------------------------------------------------------------
// Gather: one wave per node, 64 lanes x 2 fp16 channels, tanh fused.
// Chases the node's FOUR chains interleaved: 4 chain loads + 4 xt row
// fetches in flight per iteration (vs 2+2 in round 9).
// ---------------------------------------------------------------------------
__global__ __launch_bounds__(256) void gather_tanh(const int* __restrict__ head,
                                                   const int2* __restrict__ ll,
                                                   const __half* __restrict__ xt,
                                                   float* __restrict__ out) {
    const int node = (blockIdx.x * 256 + threadIdx.x) >> 6;
    if (node >= N_NODES) return;
    const int lane = threadIdx.x & 63;

    int e0 = head[node];
    int e1 = head[node + N_NODES];
    int e2 = head[node + 2 * N_NODES];
    int e3 = head[node + 3 * N_NODES];

    float ax = 0.f, ay = 0.f;
    while (e0 >= 0 || e1 >= 0 || e2 >= 0 || e3 >= 0) {
        int n0 = -1, c0 = -1, n1 = -1, c1 = -1;
        int n2 = -1, c2 = -1, n3 = -1, c3 = -1;
        if (e0 >= 0) { const int2 t = ll[e0]; n0 = t.x; c0 = t.y; }
        if (e1 >= 0) { const int2 t = ll[e1]; n1 = t.x; c1 = t.y; }
        if (e2 >= 0) { const int2 t = ll[e2]; n2 = t.x; c2 = t.y; }
        if (e3 >= 0) { const int2 t = ll[e3]; n3 = t.x; c3 = t.y; }
        if (c0 >= 0) {
            const float2 v = __half22float2(*reinterpret_cast<const __half2*>(
                &xt[(size_t)c0 * CH + lane * 2]));
            ax += v.x; ay += v.y;
        }
        if (c1 >= 0) {
            const float2 v = __half22float2(*reinterpret_cast<const __half2*>(
                &xt[(size_t)c1 * CH + lane * 2]));
            ax += v.x; ay += v.y;
        }
        if (c2 >= 0) {
            const float2 v = __half22float2(*reinterpret_cast<const __half2*>(
                &xt[(size_t)c2 * CH + lane * 2]));
            ax += v.x; ay += v.y;
        }
        if (c3 >= 0) {
            const float2 v = __half22float2(*reinterpret_cast<const __half2*>(
                &xt[(size_t)c3 * CH + lane * 2]));
            ax += v.x; ay += v.y;
        }
        e0 = n0; e1 = n1; e2 = n2; e3 = n3;
    }

    float2 o;
    o.x = tanhf(ax);
    o.y = tanhf(ay);
    *reinterpret_cast<float2*>(&out[(size_t)node * CH + lane * 2]) = o;
}

// ---------------------------------------------------------------------------
// Fallback path (ws too small): atomic scatter + tanh
// ---------------------------------------------------------------------------
__global__ __launch_bounds__(256) void scatter_add(const int* __restrict__ ei,
                                                   const __half* __restrict__ xt,
                                                   float* __restrict__ out) {
    const int gid = blockIdx.x * 256 + threadIdx.x;
    const int e = gid >> 5;
    if (e >= N_EDGES) return;
    const int lane = gid & 31;
    const int row = ei[e];
    const int col = ei[N_EDGES + e];
    const float2 va = __half22float2(*reinterpret_cast<const __half2*>(
        &xt[(size_t)col * CH + lane * 4]));
    const float2 vb = __half22float2(*reinterpret_cast<const __half2*>(
        &xt[(size_t)col * CH + lane * 4 + 2]));
    float* dst = &out[(size_t)row * CH + lane * 4];
    atomicAdd(dst + 0, va.x);
    atomicAdd(dst + 1, va.y);
    atomicAdd(dst + 2, vb.x);
    atomicAdd(dst + 3, vb.y);
}

__global__ __launch_bounds__(256) void tanh_inplace(float* __restrict__ out) {
    const int i = blockIdx.x * 256 + threadIdx.x;
    if (i < N_NODES * CH / 4) {
        float4* p = reinterpret_cast<float4*>(out);
        float4 v = p[i];
        v.x = tanhf(v.x); v.y = tanhf(v.y);
        v.z = tanhf(v.z); v.w = tanhf(v.w);
        p[i] = v;
    }
}

extern "C" void kernel_launch(void* const* d_in, const int* in_sizes, int n_in,
                              void* d_out, int out_size, void* d_ws, size_t ws_size,
                              hipStream_t stream) {
    const float* x  = (const float*)d_in[0];
    const int*   ei = (const int*)d_in[1];
    const float* W  = (const float*)d_in[2];
    const float* b  = (const float*)d_in[3];
    float* out = (float*)d_out;

    // ws layout: xt fp16 | head (4*N ints) | ll (E int2, 8B-aligned)
    const size_t XT_B    = (size_t)N_NODES * CH * sizeof(__half); // 12,800,000
    const size_t HEAD_O  = XT_B;
    size_t LL_O = HEAD_O + (size_t)(4 * N_NODES) * 4;
    LL_O = (LL_O + 255) & ~(size_t)255;
    const size_t NEED = LL_O + (size_t)N_EDGES * 8;               // ~20 MB

    __half* xt = (__half*)d_ws;

    const int rpb = 96;                                // rows per block (mult of 32)
    const int gblocks = (N_NODES + rpb - 1) / rpb;     // 521
    gemm_xt_f16<<<gblocks, 256, 0, stream>>>(x, W, b, xt, rpb);

    if (ws_size >= NEED) {
        int*  head = (int*)((char*)d_ws + HEAD_O);
        int2* ll   = (int2*)((char*)d_ws + LL_O);

        hipMemsetAsync(head, 0xFF, (size_t)(4 * N_NODES) * 4, stream);  // -1
        const int eblocks = (N_EDGES + 255) / 256;
        build_ll<<<eblocks, 256, 0, stream>>>(ei, head, ll);

        const int nblocks = (N_NODES * 64 + 255) / 256;  // one wave per node
        gather_tanh<<<nblocks, 256, 0, stream>>>(head, ll, xt, out);
    } else {
        hipMemsetAsync(d_out, 0, (size_t)N_NODES * CH * sizeof(float), stream);
        const int sblocks = (N_EDGES * 32 + 255) / 256;
        scatter_add<<<sblocks, 256, 0, stream>>>(ei, xt, out);
        const int tblocks = (N_NODES * CH / 4 + 255) / 256;
        tanh_inplace<<<tblocks, 256, 0, stream>>>(out);
    }
}

// Round 12
// 211.816 us; speedup vs baseline: 1.2361x; 1.0871x over previous
//
#include <hip/hip_runtime.h>
#include <hip/hip_bf16.h>
#include <hip/hip_fp16.h>
#include <math.h>

#define N_NODES 50000
#define N_EDGES 800000
#define CH 128

typedef __attribute__((ext_vector_type(8))) short bf16x8;
typedef __attribute__((ext_vector_type(4))) float f32x4;

static __device__ __forceinline__ short f2bf(float f) {
    unsigned u = __builtin_bit_cast(unsigned, f);
    unsigned r = (u + 0x7FFFu + ((u >> 16) & 1u)) >> 16;   // RNE
    return (short)r;
}
static __device__ __forceinline__ float bf2f(short s) {
    unsigned u = ((unsigned)(unsigned short)s) << 16;
    return __builtin_bit_cast(float, u);
}

// ---------------------------------------------------------------------------
// Kernel 1: xt (fp16) = x @ W^T + b  via SPLIT-bf16 MFMA (16x16x32, gfx950).
// Same verified fragment layout as round 11, but each operand is a bf16
// hi+lo pair (lo = bf16(f - float(hi))); acc accumulates three terms
// hi*hi + hi*lo + lo*hi -> ~1e-4 GEMM error (lo*lo ~2^-16 dropped).
// Fixes round 11's absmax 0.031 > 0.02 (bf16 input rounding tail).
// W staged once per block into LDS in fragment order (stride-1 writes &
// reads, 0 conflicts); A-fragments straight from global x.
// D layout (m89-verified): col = lane&15, row = (lane>>4)*4 + reg.
// ---------------------------------------------------------------------------
__global__ __launch_bounds__(256) void gemm_xt_mfma(const float* __restrict__ x,
                                                    const float* __restrict__ W,
                                                    const float* __restrict__ bias_p,
                                                    __half* __restrict__ xt) {
    __shared__ short  whi[2048 * 8];        // 32 KB
    __shared__ short  wlo[2048 * 8];        // 32 KB
    __shared__ float  bias_lds[128];
    __shared__ __half ostage[4][16 * 128];  // 16 KB

    const int tid  = threadIdx.x;
    const int w    = tid >> 6;
    const int lane = tid & 63;
    const int rb   = blockIdx.x * 64;

    // ---- stage W hi/lo fragments (8 chunks per thread, stride-1 writes) ----
    #pragma unroll
    for (int i = 0; i < 8; ++i) {
        const int id   = tid + (i << 8);
        const int ln   = id & 63;
        const int ctkt = id >> 6;
        const int c    = ((ctkt >> 2) << 4) + (ln & 15);
        const int k0   = ((ctkt & 3) << 5) + ((ln >> 4) << 3);
        const float4 f0 = *reinterpret_cast<const float4*>(&W[c * 128 + k0]);
        const float4 f1 = *reinterpret_cast<const float4*>(&W[c * 128 + k0 + 4]);
        bf16x8 vh, vl;
        const float ff[8] = {f0.x, f0.y, f0.z, f0.w, f1.x, f1.y, f1.z, f1.w};
        #pragma unroll
        for (int j = 0; j < 8; ++j) {
            const short h = f2bf(ff[j]);
            vh[j] = h;
            vl[j] = f2bf(ff[j] - bf2f(h));
        }
        reinterpret_cast<bf16x8*>(whi)[id] = vh;
        reinterpret_cast<bf16x8*>(wlo)[id] = vl;
    }
    if (tid < 128) bias_lds[tid] = bias_p[tid];
    __syncthreads();

    // ---- MFMA main: 4 k-tiles x 8 col-tiles, 3 terms each ----
    f32x4 acc[8];
    #pragma unroll
    for (int ct = 0; ct < 8; ++ct) acc[ct] = (f32x4){0.f, 0.f, 0.f, 0.f};

    const int arow = rb + (w << 4) + (lane & 15);
    #pragma unroll
    for (int kt = 0; kt < 4; ++kt) {
        const int k0 = (kt << 5) + ((lane >> 4) << 3);
        bf16x8 ah = {0, 0, 0, 0, 0, 0, 0, 0};
        bf16x8 al = {0, 0, 0, 0, 0, 0, 0, 0};
        if (arow < N_NODES) {
            const float4 f0 = *reinterpret_cast<const float4*>(&x[(size_t)arow * CH + k0]);
            const float4 f1 = *reinterpret_cast<const float4*>(&x[(size_t)arow * CH + k0 + 4]);
            const float ff[8] = {f0.x, f0.y, f0.z, f0.w, f1.x, f1.y, f1.z, f1.w};
            #pragma unroll
            for (int j = 0; j < 8; ++j) {
                const short h = f2bf(ff[j]);
                ah[j] = h;
                al[j] = f2bf(ff[j] - bf2f(h));
            }
        }
        #pragma unroll
        for (int ct = 0; ct < 8; ++ct) {
            const int id = ((ct << 2) + kt) * 64 + lane;
            const bf16x8 bh = reinterpret_cast<bf16x8*>(whi)[id];
            const bf16x8 bl = reinterpret_cast<bf16x8*>(wlo)[id];
            acc[ct] = __builtin_amdgcn_mfma_f32_16x16x32_bf16(ah, bh, acc[ct], 0, 0, 0);
            acc[ct] = __builtin_amdgcn_mfma_f32_16x16x32_bf16(ah, bl, acc[ct], 0, 0, 0);
            acc[ct] = __builtin_amdgcn_mfma_f32_16x16x32_bf16(al, bh, acc[ct], 0, 0, 0);
        }
    }

    // ---- epilogue: +bias, fp16, stage to own wave region ----
    #pragma unroll
    for (int ct = 0; ct < 8; ++ct) {
        const int c  = (ct << 4) + (lane & 15);
        const float bv = bias_lds[c];
        #pragma unroll
        for (int j = 0; j < 4; ++j) {
            const int r_in = ((lane >> 4) << 2) + j;
            ostage[w][r_in * 128 + c] = __float2half(acc[ct][j] + bv);
        }
    }
    __syncthreads();

    // ---- coalesced copy LDS -> global (uint4 = 8 halves) ----
    #pragma unroll
    for (int j = 0; j < 4; ++j) {
        const int cid  = (j << 6) + lane;
        const int r_in = cid >> 4;
        const int c0   = (cid & 15) << 3;
        const int grow = rb + (w << 4) + r_in;
        if (grow < N_NODES)
            *reinterpret_cast<uint4*>(&xt[(size_t)grow * CH + c0]) =
                *reinterpret_cast<const uint4*>(&ostage[w][r_in * 128 + c0]);
    }
}

// ---------------------------------------------------------------------------
// Linked-list adjacency build — FOUR chains per node (e&3). Unchanged (r10).
// ---------------------------------------------------------------------------
__global__ __launch_bounds__(256) void build_ll(const int* __restrict__ ei,
                                                int* __restrict__ head,
                                                int2* __restrict__ ll) {
    const int e = blockIdx.x * 256 + threadIdx.x;
    if (e < N_EDGES) {
        const int row = ei[e];
        const int col = ei[N_EDGES + e];
        const int h   = (e & 3) * N_NODES + row;
        const int old = atomicExch(&head[h], e);
        ll[e] = make_int2(old, col);
    }
}

// ---------------------------------------------------------------------------
// Gather: one wave per node, 4 chains interleaved, tanh fused. Unchanged (r10).
// ---------------------------------------------------------------------------
__global__ __launch_bounds__(256) void gather_tanh(const int* __restrict__ head,
                                                   const int2* __restrict__ ll,
                                                   const __half* __restrict__ xt,
                                                   float* __restrict__ out) {
    const int node = (blockIdx.x * 256 + threadIdx.x) >> 6;
    if (node >= N_NODES) return;
    const int lane = threadIdx.x & 63;

    int e0 = head[node];
    int e1 = head[node + N_NODES];
    int e2 = head[node + 2 * N_NODES];
    int e3 = head[node + 3 * N_NODES];

    float ax = 0.f, ay = 0.f;
    while (e0 >= 0 || e1 >= 0 || e2 >= 0 || e3 >= 0) {
        int n0 = -1, c0 = -1, n1 = -1, c1 = -1;
        int n2 = -1, c2 = -1, n3 = -1, c3 = -1;
        if (e0 >= 0) { const int2 t = ll[e0]; n0 = t.x; c0 = t.y; }
        if (e1 >= 0) { const int2 t = ll[e1]; n1 = t.x; c1 = t.y; }
        if (e2 >= 0) { const int2 t = ll[e2]; n2 = t.x; c2 = t.y; }
        if (e3 >= 0) { const int2 t = ll[e3]; n3 = t.x; c3 = t.y; }
        if (c0 >= 0) {
            const float2 v = __half22float2(*reinterpret_cast<const __half2*>(
                &xt[(size_t)c0 * CH + lane * 2]));
            ax += v.x; ay += v.y;
        }
        if (c1 >= 0) {
            const float2 v = __half22float2(*reinterpret_cast<const __half2*>(
                &xt[(size_t)c1 * CH + lane * 2]));
            ax += v.x; ay += v.y;
        }
        if (c2 >= 0) {
            const float2 v = __half22float2(*reinterpret_cast<const __half2*>(
                &xt[(size_t)c2 * CH + lane * 2]));
            ax += v.x; ay += v.y;
        }
        if (c3 >= 0) {
            const float2 v = __half22float2(*reinterpret_cast<const __half2*>(
                &xt[(size_t)c3 * CH + lane * 2]));
            ax += v.x; ay += v.y;
        }
        e0 = n0; e1 = n1; e2 = n2; e3 = n3;
    }

    float2 o;
    o.x = tanhf(ax);
    o.y = tanhf(ay);
    *reinterpret_cast<float2*>(&out[(size_t)node * CH + lane * 2]) = o;
}

// ---------------------------------------------------------------------------
// Fallback path (ws too small): atomic scatter + tanh
// ---------------------------------------------------------------------------
__global__ __launch_bounds__(256) void scatter_add(const int* __restrict__ ei,
                                                   const __half* __restrict__ xt,
                                                   float* __restrict__ out) {
    const int gid = blockIdx.x * 256 + threadIdx.x;
    const int e = gid >> 5;
    if (e >= N_EDGES) return;
    const int lane = gid & 31;
    const int row = ei[e];
    const int col = ei[N_EDGES + e];
    const float2 va = __half22float2(*reinterpret_cast<const __half2*>(
        &xt[(size_t)col * CH + lane * 4]));
    const float2 vb = __half22float2(*reinterpret_cast<const __half2*>(
        &xt[(size_t)col * CH + lane * 4 + 2]));
    float* dst = &out[(size_t)row * CH + lane * 4];
    atomicAdd(dst + 0, va.x);
    atomicAdd(dst + 1, va.y);
    atomicAdd(dst + 2, vb.x);
    atomicAdd(dst + 3, vb.y);
}

__global__ __launch_bounds__(256) void tanh_inplace(float* __restrict__ out) {
    const int i = blockIdx.x * 256 + threadIdx.x;
    if (i < N_NODES * CH / 4) {
        float4* p = reinterpret_cast<float4*>(out);
        float4 v = p[i];
        v.x = tanhf(v.x); v.y = tanhf(v.y);
        v.z = tanhf(v.z); v.w = tanhf(v.w);
        p[i] = v;
    }
}

extern "C" void kernel_launch(void* const* d_in, const int* in_sizes, int n_in,
                              void* d_out, int out_size, void* d_ws, size_t ws_size,
                              hipStream_t stream) {
    const float* x  = (const float*)d_in[0];
    const int*   ei = (const int*)d_in[1];
    const float* W  = (const float*)d_in[2];
    const float* b  = (const float*)d_in[3];
    float* out = (float*)d_out;

    // ws layout: xt fp16 | head (4*N ints) | ll (E int2, 8B-aligned)
    const size_t XT_B    = (size_t)N_NODES * CH * sizeof(__half); // 12,800,000
    const size_t HEAD_O  = XT_B;
    size_t LL_O = HEAD_O + (size_t)(4 * N_NODES) * 4;
    LL_O = (LL_O + 255) & ~(size_t)255;
    const size_t NEED = LL_O + (size_t)N_EDGES * 8;               // ~20 MB

    __half* xt = (__half*)d_ws;

    const int gblocks = (N_NODES + 63) / 64;           // 782
    gemm_xt_mfma<<<gblocks, 256, 0, stream>>>(x, W, b, xt);

    if (ws_size >= NEED) {
        int*  head = (int*)((char*)d_ws + HEAD_O);
        int2* ll   = (int2*)((char*)d_ws + LL_O);

        hipMemsetAsync(head, 0xFF, (size_t)(4 * N_NODES) * 4, stream);  // -1
        const int eblocks = (N_EDGES + 255) / 256;
        build_ll<<<eblocks, 256, 0, stream>>>(ei, head, ll);

        const int nblocks = (N_NODES * 64 + 255) / 256;  // one wave per node
        gather_tanh<<<nblocks, 256, 0, stream>>>(head, ll, xt, out);
    } else {
        hipMemsetAsync(d_out, 0, (size_t)N_NODES * CH * sizeof(float), stream);
        const int sblocks = (N_EDGES * 32 + 255) / 256;
        scatter_add<<<sblocks, 256, 0, stream>>>(ei, xt, out);
        const int tblocks = (N_NODES * CH / 4 + 255) / 256;
        tanh_inplace<<<tblocks, 256, 0, stream>>>(out);
    }
}